// Round 2
// baseline (360.343 us; speedup 1.0000x reference)
//
#include <hip/hip_runtime.h>
#include <hip/hip_cooperative_groups.h>

namespace cg = cooperative_groups;

namespace {

constexpr int kW = 640;
constexpr int kN = kW * 360;          // 230400
constexpr int kT = 1000;              // RANSAC planes
constexpr unsigned kSpan = 230400u;
constexpr int kBlocks = 512;
constexpr int kThreads = 256;
constexpr int kPPB = kN / kBlocks;    // 450 points per block (exact)

struct __align__(16) Acc {
  double sum_zc;
  int icnt;
  unsigned selkey;       // ordered key: ((score+2)<<10) | (1023-p)
  unsigned zmaxkey;      // ordered-key max of zc over inliers
  unsigned zminnegkey;   // ordered-key max of -zc over inliers
};

struct __align__(16) SP {              // per-block stats partial, 48 B
  double sx, sy, sz, sl;
  int cnt;
  float mx;
};

constexpr size_t kOffAcc     = 0;
constexpr size_t kOffSP      = 64;                                   // 512*48 = 24576
constexpr size_t kOffPlanes  = kOffSP + (size_t)kBlocks * sizeof(SP);// 24640
constexpr size_t kOffPartial = kOffPlanes + 16384;                   // 41024
constexpr size_t kOffPts     = kOffPartial + (size_t)kBlocks * 1024 * 2; // 1089600
// total ws use: 1089600 + 230400*16 = ~4.78 MB

__device__ __forceinline__ unsigned fkey(float f) {
  unsigned u = __float_as_uint(f);
  return (u & 0x80000000u) ? ~u : (u | 0x80000000u);
}
__device__ __forceinline__ float funkey(unsigned k) {
  unsigned u = (k & 0x80000000u) ? (k & 0x7FFFFFFFu) : ~k;
  return __uint_as_float(u);
}

__device__ __forceinline__ unsigned rotl32(unsigned v, int r) {
  return (v << r) | (v >> (32 - r));
}

// Threefry-2x32, 20 rounds, key = (0, 42)  [jax.random.key(42)]
__device__ __forceinline__ void threefry(unsigned c0, unsigned c1,
                                         unsigned& o0, unsigned& o1) {
  const unsigned ks0 = 0u, ks1 = 42u, ks2 = 0x1BD11BDAu ^ 0u ^ 42u;
  unsigned x0 = c0 + ks0, x1 = c1 + ks1;
#define TFR(r) { x0 += x1; x1 = rotl32(x1, (r)); x1 ^= x0; }
  TFR(13) TFR(15) TFR(26) TFR(6)
  x0 += ks1; x1 += ks2 + 1u;
  TFR(17) TFR(29) TFR(16) TFR(24)
  x0 += ks2; x1 += ks0 + 2u;
  TFR(13) TFR(15) TFR(26) TFR(6)
  x0 += ks0; x1 += ks1 + 3u;
  TFR(17) TFR(29) TFR(16) TFR(24)
  x0 += ks1; x1 += ks2 + 4u;
  TFR(13) TFR(15) TFR(26) TFR(6)
  x0 += ks2; x1 += ks0 + 5u;
#undef TFR
  o0 = x0; o1 = x1;
}

__device__ __forceinline__ void pix_coords(float d, int row, int col, bool& valid,
                                           float& x, float& y, float& z) {
  valid = (d > 0.0f) && (d < 65535.0f);
  float z0 = d / 1000.0f;
  float x0 = z0 * ((float)col - 334.081f) / 460.585f;
  float y0 = z0 * ((float)row - 169.808f) / 460.268f;
  x = x0 * 1000.0f;
  y = y0 * 1000.0f;
  z = z0 * 1000.0f;
  if (x == 0.0f) x = 1e-7f;
  if (y == 0.0f) y = 1e-7f;
  if (z == 0.0f) z = 1e-7f;
}

__device__ __forceinline__ float get_thresh(int ep) {
  return (float)fmax(0.025 - 0.001 * (double)ep, 0.005);
}

__global__ __launch_bounds__(kThreads, 2) void mega_kernel(
    const float* __restrict__ fake, const float* __restrict__ real,
    const int* __restrict__ epoch, float* __restrict__ out,
    char* __restrict__ ws) {
  Acc* acc = (Acc*)(ws + kOffAcc);
  SP* spart = (SP*)(ws + kOffSP);
  float4* planes = (float4*)(ws + kOffPlanes);
  unsigned short* partial = (unsigned short*)(ws + kOffPartial);
  float4* pts = (float4*)(ws + kOffPts);

  cg::grid_group grid = cg::this_grid();
  const int b = blockIdx.x, t = threadIdx.x;
  const int lane = t & 63, wid = t >> 6;

  __shared__ float4 sPts[kPPB];                 // block's 450-point slice
  __shared__ double sD0[4], sD1[4], sD2[4], sD3[4];
  __shared__ int sI0[4], sI1[4];
  __shared__ float sF0[4], sF1[4];
  __shared__ float sMaxv;
  __shared__ unsigned sBest;

  const float th = get_thresh(*epoch);

  // ---------- Phase A: masked stats over slice -> per-block partial ----------
  {
    double dx2 = 0, dy2 = 0, dz2 = 0, dl2 = 0; int cc = 0; float mx = 0.f;
    for (int k = t; k < kPPB; k += kThreads) {
      int i = b * kPPB + k;
      int row = i / kW, col = i - row * kW;
      bool vr, vf; float rx, ry, rz, fx, fy, fz;
      pix_coords(real[i], row, col, vr, rx, ry, rz);
      pix_coords(fake[i], row, col, vf, fx, fy, fz);
      if (vr && vf) {
        float ddx = rx - fx, ddy = ry - fy, ddz = rz - fz;
        dx2 += (double)ddx * (double)ddx;
        dy2 += (double)ddy * (double)ddy;
        dz2 += (double)ddz * (double)ddz;
        double dl = log(fabs((double)rz)) - log(fabs((double)fz));
        dl2 += dl * dl;
        cc++;
      }
      if (vf) mx = fmaxf(mx, fmaxf(fmaxf(fx, fy), fz));
    }
    for (int o = 32; o; o >>= 1) {
      dx2 += __shfl_down(dx2, o); dy2 += __shfl_down(dy2, o);
      dz2 += __shfl_down(dz2, o); dl2 += __shfl_down(dl2, o);
      cc += __shfl_down(cc, o);
      mx = fmaxf(mx, __shfl_down(mx, o));
    }
    if (lane == 0) { sD0[wid]=dx2; sD1[wid]=dy2; sD2[wid]=dz2; sD3[wid]=dl2;
                     sI0[wid]=cc; sF0[wid]=mx; }
    __syncthreads();
    if (t == 0) {
      SP e;
      e.sx = sD0[0]+sD0[1]+sD0[2]+sD0[3];
      e.sy = sD1[0]+sD1[1]+sD1[2]+sD1[3];
      e.sz = sD2[0]+sD2[1]+sD2[2]+sD2[3];
      e.sl = sD3[0]+sD3[1]+sD3[2]+sD3[3];
      e.cnt = sI0[0]+sI0[1]+sI0[2]+sI0[3];
      e.mx = fmaxf(fmaxf(sF0[0], sF0[1]), fmaxf(sF0[2], sF0[3]));
      spart[b] = e;
      if (b == 0) {
        acc->sum_zc = 0.0; acc->icnt = 0;
        acc->selkey = 0u; acc->zmaxkey = 0u; acc->zminnegkey = 0u;
      }
    }
  }
  grid.sync();

  // ---------- Phase B: global max (redundant reduce) + materialize pts ----------
  {
    float m = fmaxf(spart[t].mx, spart[t + kThreads].mx);
    for (int o = 32; o; o >>= 1) m = fmaxf(m, __shfl_down(m, o));
    if (lane == 0) sF1[wid] = m;
    __syncthreads();
    if (t == 0) sMaxv = fmaxf(fmaxf(sF1[0], sF1[1]), fmaxf(sF1[2], sF1[3]));
    __syncthreads();
    float maxv = sMaxv;
    for (int k = t; k < kPPB; k += kThreads) {
      int i = b * kPPB + k;
      int row = i / kW, col = i - row * kW;
      bool vf; float fx, fy, fz;
      pix_coords(fake[i], row, col, vf, fx, fy, fz);
      float4 q = make_float4((vf ? fx : 0.f) / maxv, (vf ? fy : 0.f) / maxv,
                             (vf ? fz : 0.f) / maxv, 0.f);
      sPts[k] = q;      // stays resident for phases D and F
      pts[i] = q;       // global copy for the random gathers in phase C
    }
  }
  grid.sync();

  // ---------- Phase C: each thread builds its 4 planes (registers) ----------
  float4 pl[4];
  {
#pragma unroll
    for (int j = 0; j < 4; j++) {
      int pid = t * 4 + j;
      if (pid < kT) {
        float px[3], py[3], pz[3];
#pragma unroll
        for (int v = 0; v < 3; v++) {
          unsigned p = 3u * (unsigned)pid + (unsigned)v;
          unsigned o0, o1;
          threefry(p, p + 3000u, o0, o1);   // lower bits word; multiplier wraps to 0
          float4 q = pts[o1 % kSpan];
          px[v] = q.x; py[v] = q.y; pz[v] = q.z;
        }
        float ax = px[1]-px[0], ay = py[1]-py[0], az = pz[1]-pz[0];
        float bx = px[2]-px[0], by = py[2]-py[0], bz = pz[2]-pz[0];
        float nx = ay*bz - az*by;
        float ny = az*bx - ax*bz;
        float nz = ax*by - ay*bx;
        float nn = sqrtf(nx*nx + ny*ny + nz*nz);
        nx /= nn; ny /= nn; nz /= nn;
        float kk = -(nx*px[1] + ny*py[1] + nz*pz[1]);
        pl[j] = make_float4(nx, ny, nz, kk);
        if (b == 0) planes[pid] = pl[j];     // canonical copy for phase F
      } else {
        pl[j] = make_float4(0.f, 0.f, 0.f, 3e38f);  // dummy: never inlier
      }
    }
  }

  // ---------- Phase D: count inliers, slice(LDS) x 4 planes; store partials ----------
  {
    int c0 = 0, c1 = 0, c2 = 0, c3 = 0;
#pragma unroll 10
    for (int s = 0; s < kPPB; s++) {
      float4 q = sPts[s];
      float d0 = fmaf(q.x, pl[0].x, fmaf(q.y, pl[0].y, fmaf(q.z, pl[0].z, pl[0].w)));
      float d1 = fmaf(q.x, pl[1].x, fmaf(q.y, pl[1].y, fmaf(q.z, pl[1].z, pl[1].w)));
      float d2 = fmaf(q.x, pl[2].x, fmaf(q.y, pl[2].y, fmaf(q.z, pl[2].z, pl[2].w)));
      float d3 = fmaf(q.x, pl[3].x, fmaf(q.y, pl[3].y, fmaf(q.z, pl[3].z, pl[3].w)));
      c0 += (fabsf(d0) <= th) ? 1 : 0;
      c1 += (fabsf(d1) <= th) ? 1 : 0;
      c2 += (fabsf(d2) <= th) ? 1 : 0;
      c3 += (fabsf(d3) <= th) ? 1 : 0;
    }
    ((ushort4*)partial)[(size_t)b * kThreads + t] =
        make_ushort4((unsigned short)c0, (unsigned short)c1,
                     (unsigned short)c2, (unsigned short)c3);
  }
  grid.sync();

  // ---------- Phase E: distributed select (2 planes per block) ----------
  if (b < kT / 2) {
    int p0 = 2 * b, p1 = 2 * b + 1;
    int a0 = 0, a1 = 0;
    for (int k = t; k < kBlocks; k += kThreads) {
      const unsigned short* rowp = partial + (size_t)k * 1024;
      a0 += rowp[p0];
      a1 += rowp[p1];
    }
    for (int o = 32; o; o >>= 1) { a0 += __shfl_down(a0, o); a1 += __shfl_down(a1, o); }
    if (lane == 0) { sI0[wid] = a0; sI1[wid] = a1; }
    __syncthreads();
    if (t == 0) {
      int t0 = sI0[0]+sI0[1]+sI0[2]+sI0[3];
      int t1 = sI1[0]+sI1[1]+sI1[2]+sI1[3];
      int s0 = (t0 > 5000) ? t0 : -1;     // MIN_POINTS=5000, strict >
      int s1 = (t1 > 5000) ? t1 : -1;
      unsigned k0 = ((unsigned)(s0 + 2) << 10) | (unsigned)(1023 - p0);
      unsigned k1 = ((unsigned)(s1 + 2) << 10) | (unsigned)(1023 - p1);
      atomicMax(&acc->selkey, k0 > k1 ? k0 : k1);  // argmax, first index on ties
    }
  }
  grid.sync();

  // ---------- Phase F: zc reduction over inliers of best plane ----------
  {
    if (t == 0) sBest = acc->selkey;
    __syncthreads();
    int bestp = 1023 - (int)(sBest & 1023u);
    float4 bp = planes[bestp];
    float a = bp.x, bb = bp.y, c = bp.z, d = bp.w;
    float n2 = a*a + bb*bb + c*c;
    float cos_t = c / sqrtf(n2);
    float sin_t = sqrtf((a*a + bb*bb) / n2);
    float sab = sqrtf(a*a + bb*bb);
    float u1 = bb / sab, u2 = -a / sab;
    float r0 = -u2 * sin_t, r1 = u1 * sin_t, r2 = cos_t, tz = d / c;

    double sz = 0.0; int ic = 0; float zmx = -INFINITY, zmn = -INFINITY; // zmn=max(-zc)
    for (int k = t; k < kPPB; k += kThreads) {
      float4 q = sPts[k];
      // identical fmaf chain to phase D -> identical inlier mask
      float dist = fmaf(q.x, a, fmaf(q.y, bb, fmaf(q.z, c, d)));
      if (fabsf(dist) <= th) {
        float zc = fmaf(q.x, r0, fmaf(q.y, r1, (q.z + tz) * r2));
        sz += (double)zc; ic++;
        zmx = fmaxf(zmx, zc);
        zmn = fmaxf(zmn, -zc);
      }
    }
    for (int o = 32; o; o >>= 1) {
      sz += __shfl_down(sz, o); ic += __shfl_down(ic, o);
      zmx = fmaxf(zmx, __shfl_down(zmx, o));
      zmn = fmaxf(zmn, __shfl_down(zmn, o));
    }
    if (lane == 0) { sD0[wid] = sz; sI0[wid] = ic; sF0[wid] = zmx; sF1[wid] = zmn; }
    __syncthreads();
    if (t == 0) {
      double bsz = sD0[0]+sD0[1]+sD0[2]+sD0[3];
      int bic = sI0[0]+sI0[1]+sI0[2]+sI0[3];
      float bmx = fmaxf(fmaxf(sF0[0], sF0[1]), fmaxf(sF0[2], sF0[3]));
      float bmn = fmaxf(fmaxf(sF1[0], sF1[1]), fmaxf(sF1[2], sF1[3]));
      if (bic > 0) {
        atomicAdd(&acc->sum_zc, bsz);
        atomicAdd(&acc->icnt, bic);
        atomicMax(&acc->zmaxkey, fkey(bmx));
        atomicMax(&acc->zminnegkey, fkey(bmn));
      }
    }
  }
  grid.sync();

  // ---------- Phase G: final scalars (block 0) ----------
  if (b == 0) {
    double sx = 0, sy = 0, sz2 = 0, sl = 0; int cn = 0;
    for (int k = t; k < kBlocks; k += kThreads) {
      SP e = spart[k];
      sx += e.sx; sy += e.sy; sz2 += e.sz; sl += e.sl; cn += e.cnt;
    }
    for (int o = 32; o; o >>= 1) {
      sx += __shfl_down(sx, o); sy += __shfl_down(sy, o);
      sz2 += __shfl_down(sz2, o); sl += __shfl_down(sl, o);
      cn += __shfl_down(cn, o);
    }
    if (lane == 0) { sD0[wid]=sx; sD1[wid]=sy; sD2[wid]=sz2; sD3[wid]=sl; sI0[wid]=cn; }
    __syncthreads();
    if (t == 0) {
      double SX = sD0[0]+sD0[1]+sD0[2]+sD0[3];
      double SY = sD1[0]+sD1[1]+sD1[2]+sD1[3];
      double SZ = sD2[0]+sD2[1]+sD2[2]+sD2[3];
      double SL = sD3[0]+sD3[1]+sD3[2]+sD3[3];
      int CN = sI0[0]+sI0[1]+sI0[2]+sI0[3];
      double cntd = (CN > 0) ? (double)CN : 1.0;
      double lossX = sqrt(SX / cntd);
      double lossY = sqrt(SY / cntd);
      double lossZ = sqrt(SZ / cntd);
      double rmse_log = 10000.0 * sqrt(SL / cntd);
      double loss17 = rmse_log * fabs(10.0 * (3.0 - exp(lossX) - exp(lossY) - exp(lossZ)));
      int ic = acc->icnt;
      double below = 0.0, above = 0.0;
      if (ic > 0) {
        double icd = (double)ic;
        double mean = acc->sum_zc / icd;
        double zmax = (double)funkey(acc->zmaxkey);
        double zmin = -(double)funkey(acc->zminnegkey);
        below = zmax - mean;   // sum(|zc - zmax|)/icnt
        above = mean - zmin;   // sum(|zc - zmin|)/icnt
      }
      if (above == 0.0) above = 1e-7;
      double pmdg = 1000.0 * (above + below);
      double loss_curv = loss17 + pmdg;
      out[0] = (float)rmse_log;
      out[1] = (float)lossX;
      out[2] = (float)lossY;
      out[3] = (float)lossZ;
      out[4] = (float)pmdg;
      out[5] = (float)loss17;
      out[6] = (float)loss_curv;
    }
  }
}

}  // namespace

extern "C" void kernel_launch(void* const* d_in, const int* in_sizes, int n_in,
                              void* d_out, int out_size, void* d_ws, size_t ws_size,
                              hipStream_t stream) {
  (void)in_sizes; (void)n_in; (void)out_size; (void)ws_size;
  const float* fake = (const float*)d_in[0];
  const float* real = (const float*)d_in[1];
  const int* epoch = (const int*)d_in[2];
  float* out = (float*)d_out;
  char* ws = (char*)d_ws;

  void* args[] = { (void*)&fake, (void*)&real, (void*)&epoch, (void*)&out, (void*)&ws };
  hipLaunchCooperativeKernel(reinterpret_cast<void*>(&mega_kernel),
                             dim3(kBlocks), dim3(kThreads), args, 0, stream);
}

// Round 3
// 326.394 us; speedup vs baseline: 1.1040x; 1.1040x over previous
//
#include <hip/hip_runtime.h>

namespace {

typedef float v2f __attribute__((ext_vector_type(2)));

constexpr int kW = 640;
constexpr int kN = 230400;            // 360*640
constexpr unsigned kSpan = 230400u;
constexpr int kBlk = 900;             // 900 blocks x 256 threads = kN
constexpr unsigned kPoison = 0xAAAAAAAAu;

struct __align__(16) Acc {
  double sum_zc;
  double lossX, lossY, lossZ, rmse_log, loss17;
  float maxv;
  int icnt;
  unsigned selkey;       // ((score+2)<<10) | (1023-plane)
  unsigned zmaxkey;      // ordered-key max of zc over inliers
  unsigned zminnegkey;   // ordered-key max of -zc over inliers
  int doneK3;
  int doneK4;
  int pad;
};

struct __align__(16) SP { double sx, sy, sz, sl; int cnt; float mx; double pad; };

// ws layout
constexpr size_t kOffAcc     = 0;        // ~112 B
constexpr size_t kOffDoneK1  = 128;      // unsigned, poison-based counter
constexpr size_t kOffPlanes  = 256;      // 1024 * 16 = 16384
constexpr size_t kOffSP      = 16640;    // 900 * 48  = 43200
constexpr size_t kOffPartial = 59904;    // 900 * 1024 * 2 = 1,843,200  (~1.9 MB total)

__device__ __forceinline__ unsigned fkey(float f) {
  unsigned u = __float_as_uint(f);
  return (u & 0x80000000u) ? ~u : (u | 0x80000000u);
}
__device__ __forceinline__ float funkey(unsigned k) {
  unsigned u = (k & 0x80000000u) ? (k & 0x7FFFFFFFu) : ~k;
  return __uint_as_float(u);
}

__device__ __forceinline__ unsigned rotl32(unsigned v, int r) {
  return (v << r) | (v >> (32 - r));
}

// Threefry-2x32, 20 rounds, key = (0, 42)  [jax.random.key(42)]
__device__ __forceinline__ void threefry(unsigned c0, unsigned c1,
                                         unsigned& o0, unsigned& o1) {
  const unsigned ks0 = 0u, ks1 = 42u, ks2 = 0x1BD11BDAu ^ 0u ^ 42u;
  unsigned x0 = c0 + ks0, x1 = c1 + ks1;
#define TFR(r) { x0 += x1; x1 = rotl32(x1, (r)); x1 ^= x0; }
  TFR(13) TFR(15) TFR(26) TFR(6)
  x0 += ks1; x1 += ks2 + 1u;
  TFR(17) TFR(29) TFR(16) TFR(24)
  x0 += ks2; x1 += ks0 + 2u;
  TFR(13) TFR(15) TFR(26) TFR(6)
  x0 += ks0; x1 += ks1 + 3u;
  TFR(17) TFR(29) TFR(16) TFR(24)
  x0 += ks1; x1 += ks2 + 4u;
  TFR(13) TFR(15) TFR(26) TFR(6)
  x0 += ks2; x1 += ks0 + 5u;
#undef TFR
  o0 = x0; o1 = x1;
}

__device__ __forceinline__ void pix_coords(float d, int row, int col, bool& valid,
                                           float& x, float& y, float& z) {
  valid = (d > 0.0f) && (d < 65535.0f);
  float z0 = d / 1000.0f;
  float x0 = z0 * ((float)col - 334.081f) / 460.585f;
  float y0 = z0 * ((float)row - 169.808f) / 460.268f;
  x = x0 * 1000.0f;
  y = y0 * 1000.0f;
  z = z0 * 1000.0f;
  if (x == 0.0f) x = 1e-7f;
  if (y == 0.0f) y = 1e-7f;
  if (z == 0.0f) z = 1e-7f;
}

__device__ __forceinline__ float get_thresh(int ep) {
  return (float)fmax(0.025 - 0.001 * (double)ep, 0.005);
}

// ============ K1: stats partials; last block reduces + builds planes ============
__global__ __launch_bounds__(256) void k_stats(const float* __restrict__ fake,
                                               const float* __restrict__ real,
                                               char* __restrict__ ws) {
  Acc* acc = (Acc*)(ws + kOffAcc);
  unsigned* doneK1 = (unsigned*)(ws + kOffDoneK1);
  float4* planes = (float4*)(ws + kOffPlanes);
  SP* sp = (SP*)(ws + kOffSP);

  const int b = blockIdx.x, t = threadIdx.x;
  const int lane = t & 63, wid = t >> 6;

  __shared__ double sD0[4], sD1[4], sD2[4], sD3[4];
  __shared__ int sI0[4];
  __shared__ float sF0[4];
  __shared__ unsigned sArr;
  __shared__ float sMaxv;

  // ---- per-block masked stats (1 point / thread) ----
  {
    int i = b * 256 + t;
    int row = i / kW, col = i - row * kW;
    bool vr, vf; float rx, ry, rz, fx, fy, fz;
    pix_coords(real[i], row, col, vr, rx, ry, rz);
    pix_coords(fake[i], row, col, vf, fx, fy, fz);
    double dx2 = 0, dy2 = 0, dz2 = 0, dl2 = 0; int cc = 0;
    if (vr && vf) {
      float ddx = rx - fx, ddy = ry - fy, ddz = rz - fz;
      dx2 = (double)ddx * (double)ddx;
      dy2 = (double)ddy * (double)ddy;
      dz2 = (double)ddz * (double)ddz;
      double dl = log(fabs((double)rz)) - log(fabs((double)fz));
      dl2 = dl * dl;
      cc = 1;
    }
    float mx = vf ? fmaxf(fmaxf(fx, fy), fz) : 0.0f;
    for (int o = 32; o; o >>= 1) {
      dx2 += __shfl_down(dx2, o); dy2 += __shfl_down(dy2, o);
      dz2 += __shfl_down(dz2, o); dl2 += __shfl_down(dl2, o);
      cc += __shfl_down(cc, o);
      mx = fmaxf(mx, __shfl_down(mx, o));
    }
    if (lane == 0) { sD0[wid]=dx2; sD1[wid]=dy2; sD2[wid]=dz2; sD3[wid]=dl2;
                     sI0[wid]=cc; sF0[wid]=mx; }
    __syncthreads();
    if (t == 0) {
      SP e;
      e.sx = sD0[0]+sD0[1]+sD0[2]+sD0[3];
      e.sy = sD1[0]+sD1[1]+sD1[2]+sD1[3];
      e.sz = sD2[0]+sD2[1]+sD2[2]+sD2[3];
      e.sl = sD3[0]+sD3[1]+sD3[2]+sD3[3];
      e.cnt = sI0[0]+sI0[1]+sI0[2]+sI0[3];
      e.mx = fmaxf(fmaxf(sF0[0], sF0[1]), fmaxf(sF0[2], sF0[3]));
      e.pad = 0.0;
      sp[b] = e;
    }
  }
  __threadfence();   // release my stores device-wide
  __syncthreads();
  if (t == 0)
    sArr = __hip_atomic_fetch_add(doneK1, 1u, __ATOMIC_ACQ_REL,
                                  __HIP_MEMORY_SCOPE_AGENT);
  __syncthreads();
  unsigned arr = sArr;
  // last arrival => every other block's release-fence has completed
  if (arr != kPoison + (unsigned)(kBlk - 1) && arr != (unsigned)(kBlk - 1)) return;

  // ---------------- tail: final stats reduce + plane build ----------------
  __threadfence();   // acquire
  {
    double gx = 0, gy = 0, gz = 0, gl = 0; int gc = 0; float gm = 0.f;
    for (int k = t; k < kBlk; k += 256) {
      SP e = sp[k];
      gx += e.sx; gy += e.sy; gz += e.sz; gl += e.sl; gc += e.cnt;
      gm = fmaxf(gm, e.mx);
    }
    for (int o = 32; o; o >>= 1) {
      gx += __shfl_down(gx, o); gy += __shfl_down(gy, o);
      gz += __shfl_down(gz, o); gl += __shfl_down(gl, o);
      gc += __shfl_down(gc, o);
      gm = fmaxf(gm, __shfl_down(gm, o));
    }
    if (lane == 0) { sD0[wid]=gx; sD1[wid]=gy; sD2[wid]=gz; sD3[wid]=gl;
                     sI0[wid]=gc; sF0[wid]=gm; }
    __syncthreads();
    if (t == 0) {
      double SX = sD0[0]+sD0[1]+sD0[2]+sD0[3];
      double SY = sD1[0]+sD1[1]+sD1[2]+sD1[3];
      double SZ = sD2[0]+sD2[1]+sD2[2]+sD2[3];
      double SL = sD3[0]+sD3[1]+sD3[2]+sD3[3];
      int CN = sI0[0]+sI0[1]+sI0[2]+sI0[3];
      float MX = fmaxf(fmaxf(sF0[0], sF0[1]), fmaxf(sF0[2], sF0[3]));
      double cntd = (CN > 0) ? (double)CN : 1.0;
      double lossX = sqrt(SX / cntd);
      double lossY = sqrt(SY / cntd);
      double lossZ = sqrt(SZ / cntd);
      double rmse_log = 10000.0 * sqrt(SL / cntd);
      double loss17 = rmse_log * fabs(10.0 * (3.0 - exp(lossX) - exp(lossY) - exp(lossZ)));
      acc->lossX = lossX; acc->lossY = lossY; acc->lossZ = lossZ;
      acc->rmse_log = rmse_log; acc->loss17 = loss17;
      acc->maxv = MX;
      acc->sum_zc = 0.0; acc->icnt = 0;
      acc->selkey = 0u; acc->zmaxkey = 0u; acc->zminnegkey = 0u;
      acc->doneK3 = 0; acc->doneK4 = 0;
      sMaxv = MX;
    }
    __syncthreads();
  }
  {
    float maxv = sMaxv;
#pragma unroll
    for (int j = 0; j < 4; j++) {
      int pid = t * 4 + j;
      if (pid < 1000) {
        float px[3], py[3], pz[3];
#pragma unroll
        for (int v = 0; v < 3; v++) {
          unsigned p = 3u * (unsigned)pid + (unsigned)v;
          unsigned o0, o1;
          threefry(p, p + 3000u, o0, o1);     // JAX randint: mult wraps to 0 => o1 % span
          unsigned idx = o1 % kSpan;
          int row = (int)(idx / kW), col = (int)idx - row * kW;
          bool vf; float fx, fy, fz;
          pix_coords(fake[idx], row, col, vf, fx, fy, fz);
          px[v] = (vf ? fx : 0.f) / maxv;
          py[v] = (vf ? fy : 0.f) / maxv;
          pz[v] = (vf ? fz : 0.f) / maxv;
        }
        float ax = px[1]-px[0], ay = py[1]-py[0], az = pz[1]-pz[0];
        float bx = px[2]-px[0], by = py[2]-py[0], bz = pz[2]-pz[0];
        float nx = ay*bz - az*by;
        float ny = az*bx - ax*bz;
        float nz = ax*by - ay*bx;
        float nn = sqrtf(nx*nx + ny*ny + nz*nz);
        nx /= nn; ny /= nn; nz /= nn;
        float kk = -(nx*px[1] + ny*py[1] + nz*pz[1]);
        planes[pid] = make_float4(nx, ny, nz, kk);
      } else {
        planes[pid] = make_float4(0.f, 0.f, 0.f, 3e38f);  // dummy: never inlier
      }
    }
  }
}

// ============ K3: inlier count (partial stores); last-8 blocks select ============
__global__ __launch_bounds__(256) void k_count(const float* __restrict__ fake,
                                               const int* __restrict__ epoch,
                                               char* __restrict__ ws) {
  Acc* acc = (Acc*)(ws + kOffAcc);
  float4* planes = (float4*)(ws + kOffPlanes);
  unsigned short* partial = (unsigned short*)(ws + kOffPartial);

  const int b = blockIdx.x, t = threadIdx.x;
  const float th = get_thresh(*epoch);
  const float maxv = acc->maxv;

  __shared__ float4 sPts[256];
  __shared__ int sArr;
  __shared__ int sSum[256];
  __shared__ unsigned sKey[2];

  {
    int i = b * 256 + t;
    int row = i / kW, col = i - row * kW;
    bool vf; float fx, fy, fz;
    pix_coords(fake[i], row, col, vf, fx, fy, fz);
    sPts[t] = make_float4((vf ? fx : 0.f) / maxv, (vf ? fy : 0.f) / maxv,
                          (vf ? fz : 0.f) / maxv, 0.f);
  }
  int base = t * 4;
  float4 p0 = planes[base + 0], p1 = planes[base + 1];
  float4 p2 = planes[base + 2], p3 = planes[base + 3];
  v2f ax = {p0.x, p1.x}, ay = {p0.y, p1.y}, az = {p0.z, p1.z}, aw = {p0.w, p1.w};
  v2f bx = {p2.x, p3.x}, by = {p2.y, p3.y}, bz = {p2.z, p3.z}, bw = {p2.w, p3.w};
  __syncthreads();

  int c0 = 0, c1 = 0, c2 = 0, c3 = 0;
#pragma unroll 8
  for (int s = 0; s < 256; s++) {
    float4 q = sPts[s];
    v2f qx = {q.x, q.x}, qy = {q.y, q.y}, qz = {q.z, q.z};
    // per-lane IEEE identical to scalar fmaf chain (mask-consistent with k_zc)
    v2f dA = __builtin_elementwise_fma(qx, ax,
             __builtin_elementwise_fma(qy, ay,
             __builtin_elementwise_fma(qz, az, aw)));
    v2f dB = __builtin_elementwise_fma(qx, bx,
             __builtin_elementwise_fma(qy, by,
             __builtin_elementwise_fma(qz, bz, bw)));
    c0 += (fabsf(dA.x) <= th) ? 1 : 0;
    c1 += (fabsf(dA.y) <= th) ? 1 : 0;
    c2 += (fabsf(dB.x) <= th) ? 1 : 0;
    c3 += (fabsf(dB.y) <= th) ? 1 : 0;
  }
  ((ushort4*)partial)[b * 256 + t] =
      make_ushort4((unsigned short)c0, (unsigned short)c1,
                   (unsigned short)c2, (unsigned short)c3);

  __threadfence();
  __syncthreads();
  if (t == 0)
    sArr = __hip_atomic_fetch_add(&acc->doneK3, 1, __ATOMIC_ACQ_REL,
                                  __HIP_MEMORY_SCOPE_AGENT);
  __syncthreads();
  int ret = sArr;
  if (ret < kBlk - 8) return;

  // ---- distributed select: last 8 arrivals, 128 plane slots each ----
  int r = ret - (kBlk - 8);
  while (__hip_atomic_load(&acc->doneK3, __ATOMIC_ACQUIRE,
                           __HIP_MEMORY_SCOPE_AGENT) < kBlk)
    __builtin_amdgcn_s_sleep(8);
  __threadfence();

  int slot = r * 128 + (t & 127);
  int half = t >> 7;                    // 0 or 1: split 900 count-blocks
  int sum = 0;
  for (int bb = half * 450; bb < half * 450 + 450; ++bb)
    sum += (int)partial[bb * 1024 + slot];
  sSum[t] = sum;
  __syncthreads();
  unsigned key = 0u;
  if (t < 128) {
    int total = sSum[t] + sSum[t + 128];
    int score = (total > 5000) ? total : -1;      // MIN_POINTS, strict >
    key = ((unsigned)(score + 2) << 10) | (unsigned)(1023 - slot);
    for (int o = 32; o; o >>= 1) {
      unsigned other = __shfl_down(key, o);
      key = key > other ? key : other;
    }
  }
  if (t < 128 && (t & 63) == 0) sKey[t >> 6] = key;
  __syncthreads();
  if (t == 0) {
    unsigned k0 = sKey[0], k1 = sKey[1];
    atomicMax(&acc->selkey, k0 > k1 ? k0 : k1);
  }
}

// ============ K4: zc reduction over best plane's inliers; last block finalizes ============
__global__ __launch_bounds__(256) void k_zc(const float* __restrict__ fake,
                                            const int* __restrict__ epoch,
                                            float* __restrict__ out,
                                            char* __restrict__ ws) {
  Acc* acc = (Acc*)(ws + kOffAcc);
  float4* planes = (float4*)(ws + kOffPlanes);

  const int b = blockIdx.x, t = threadIdx.x;
  const int lane = t & 63, wid = t >> 6;
  const float th = get_thresh(*epoch);
  const float maxv = acc->maxv;

  __shared__ double sD0[4];
  __shared__ int sI0[4];
  __shared__ float sF0[4], sF1[4];
  __shared__ int sArr;

  int best = 1023 - (int)(acc->selkey & 1023u);
  float4 bp = planes[best];
  float a = bp.x, bb2 = bp.y, c = bp.z, d = bp.w;
  float n2 = a * a + bb2 * bb2 + c * c;
  float cos_t = c / sqrtf(n2);
  float sin_t = sqrtf((a * a + bb2 * bb2) / n2);
  float sab = sqrtf(a * a + bb2 * bb2);
  float u1 = bb2 / sab, u2 = -a / sab;
  float r0 = -u2 * sin_t, r1 = u1 * sin_t, r2 = cos_t, tz = d / c;

  double sz = 0.0; int ic = 0; float zmx = -INFINITY, zmn = -INFINITY;
  {
    int i = b * 256 + t;
    int row = i / kW, col = i - row * kW;
    bool vf; float fx, fy, fz;
    pix_coords(fake[i], row, col, vf, fx, fy, fz);
    float qx = (vf ? fx : 0.f) / maxv;
    float qy = (vf ? fy : 0.f) / maxv;
    float qz = (vf ? fz : 0.f) / maxv;
    float dist = fmaf(qx, a, fmaf(qy, bb2, fmaf(qz, c, d)));   // == k_count chain
    if (fabsf(dist) <= th) {
      float zc = fmaf(qx, r0, fmaf(qy, r1, (qz + tz) * r2));
      sz = (double)zc; ic = 1; zmx = zc; zmn = -zc;
    }
  }
  for (int o = 32; o; o >>= 1) {
    sz += __shfl_down(sz, o); ic += __shfl_down(ic, o);
    zmx = fmaxf(zmx, __shfl_down(zmx, o));
    zmn = fmaxf(zmn, __shfl_down(zmn, o));
  }
  if (lane == 0) { sD0[wid] = sz; sI0[wid] = ic; sF0[wid] = zmx; sF1[wid] = zmn; }
  __syncthreads();
  if (t == 0) {
    double bsz = sD0[0]+sD0[1]+sD0[2]+sD0[3];
    int bic = sI0[0]+sI0[1]+sI0[2]+sI0[3];
    float bmx = fmaxf(fmaxf(sF0[0], sF0[1]), fmaxf(sF0[2], sF0[3]));
    float bmn = fmaxf(fmaxf(sF1[0], sF1[1]), fmaxf(sF1[2], sF1[3]));
    if (bic > 0) {
      atomicAdd(&acc->sum_zc, bsz);
      atomicAdd(&acc->icnt, bic);
      atomicMax(&acc->zmaxkey, fkey(bmx));
      atomicMax(&acc->zminnegkey, fkey(bmn));
    }
  }
  __threadfence();
  __syncthreads();
  if (t == 0)
    sArr = __hip_atomic_fetch_add(&acc->doneK4, 1, __ATOMIC_ACQ_REL,
                                  __HIP_MEMORY_SCOPE_AGENT);
  __syncthreads();
  if (sArr != kBlk - 1 || t != 0) return;

  // ---- final scalars ----
  __threadfence();
  int icf = acc->icnt;
  double below = 0.0, above = 0.0;
  if (icf > 0) {
    double icd = (double)icf;
    double mean = acc->sum_zc / icd;
    double zmax = (double)funkey(acc->zmaxkey);
    double zmin = -(double)funkey(acc->zminnegkey);
    below = zmax - mean;   // sum(|zc - zmax|)/icnt  (all zc <= zmax)
    above = mean - zmin;   // sum(|zc - zmin|)/icnt
  }
  if (above == 0.0) above = 1e-7;
  double pmdg = 1000.0 * (above + below);
  double loss17 = acc->loss17;
  out[0] = (float)acc->rmse_log;
  out[1] = (float)acc->lossX;
  out[2] = (float)acc->lossY;
  out[3] = (float)acc->lossZ;
  out[4] = (float)pmdg;
  out[5] = (float)loss17;
  out[6] = (float)(loss17 + pmdg);
}

}  // namespace

extern "C" void kernel_launch(void* const* d_in, const int* in_sizes, int n_in,
                              void* d_out, int out_size, void* d_ws, size_t ws_size,
                              hipStream_t stream) {
  (void)in_sizes; (void)n_in; (void)out_size; (void)ws_size;
  const float* fake = (const float*)d_in[0];
  const float* real = (const float*)d_in[1];
  const int* epoch = (const int*)d_in[2];
  float* out = (float*)d_out;
  char* ws = (char*)d_ws;

  k_stats<<<kBlk, 256, 0, stream>>>(fake, real, ws);
  k_count<<<kBlk, 256, 0, stream>>>(fake, epoch, ws);
  k_zc<<<kBlk, 256, 0, stream>>>(fake, epoch, out, ws);
}

// Round 4
// 180.058 us; speedup vs baseline: 2.0013x; 1.8127x over previous
//
#include <hip/hip_runtime.h>

namespace {

typedef float v2f __attribute__((ext_vector_type(2)));

constexpr int kW = 640;
constexpr int kN = 230400;            // 360*640
constexpr unsigned kSpan = 230400u;
constexpr int kB1 = 900;              // stats blocks (256 pts each)
constexpr int kB3 = 450;              // count blocks (512 pts each)
constexpr int kB5 = 900;              // zc blocks (256 pts each)
constexpr unsigned kPoison = 0xAAAAAAAAu;

struct __align__(16) Acc {            // plain data, handed across kernels via stream order
  double lossX, lossY, lossZ, rmse_log, loss17;
  float maxv;
  float pa, pb, pc, pd;               // best plane
  float r0, r1, r2, tz;               // rotation row 2 + translation z
};

// ws layout (bytes)
constexpr size_t kOffAcc    = 0;
constexpr size_t kOffC1     = 256;     // poison-based arrival counters
constexpr size_t kOffC3     = 320;
constexpr size_t kOffC5     = 384;
constexpr size_t kOffPlanes = 512;                      // 1000*16 = 16000 (pad 16384)
constexpr size_t kOffSP     = 512 + 16384;              // 900 * 48 B
constexpr size_t kOffZP     = kOffSP + 43200;           // 900 * 32 B
constexpr size_t kOffRows   = kOffZP + 28800;           // 450 * 2048 B = 921600

__device__ __forceinline__ void ast64(unsigned long long* p, unsigned long long v) {
  __hip_atomic_store(p, v, __ATOMIC_RELAXED, __HIP_MEMORY_SCOPE_AGENT);
}
__device__ __forceinline__ unsigned long long ald64(const unsigned long long* p) {
  return __hip_atomic_load(p, __ATOMIC_RELAXED, __HIP_MEMORY_SCOPE_AGENT);
}

__device__ __forceinline__ unsigned rotl32(unsigned v, int r) {
  return (v << r) | (v >> (32 - r));
}

// Threefry-2x32, 20 rounds, key = (0, 42)  [jax.random.key(42)]
__device__ __forceinline__ void threefry(unsigned c0, unsigned c1,
                                         unsigned& o0, unsigned& o1) {
  const unsigned ks0 = 0u, ks1 = 42u, ks2 = 0x1BD11BDAu ^ 0u ^ 42u;
  unsigned x0 = c0 + ks0, x1 = c1 + ks1;
#define TFR(r) { x0 += x1; x1 = rotl32(x1, (r)); x1 ^= x0; }
  TFR(13) TFR(15) TFR(26) TFR(6)
  x0 += ks1; x1 += ks2 + 1u;
  TFR(17) TFR(29) TFR(16) TFR(24)
  x0 += ks2; x1 += ks0 + 2u;
  TFR(13) TFR(15) TFR(26) TFR(6)
  x0 += ks0; x1 += ks1 + 3u;
  TFR(17) TFR(29) TFR(16) TFR(24)
  x0 += ks1; x1 += ks2 + 4u;
  TFR(13) TFR(15) TFR(26) TFR(6)
  x0 += ks2; x1 += ks0 + 5u;
#undef TFR
  o0 = x0; o1 = x1;
}

__device__ __forceinline__ void pix_coords(float d, int row, int col, bool& valid,
                                           float& x, float& y, float& z) {
  valid = (d > 0.0f) && (d < 65535.0f);
  float z0 = d / 1000.0f;
  float x0 = z0 * ((float)col - 334.081f) / 460.585f;
  float y0 = z0 * ((float)row - 169.808f) / 460.268f;
  x = x0 * 1000.0f;
  y = y0 * 1000.0f;
  z = z0 * 1000.0f;
  if (x == 0.0f) x = 1e-7f;
  if (y == 0.0f) y = 1e-7f;
  if (z == 0.0f) z = 1e-7f;
}

// normalized pts row — MUST be the identical expression in k_count and k_zc
__device__ __forceinline__ void make_pt(float d, int row, int col, float maxv,
                                        float& x, float& y, float& z) {
  bool v; float a, b, c;
  pix_coords(d, row, col, v, a, b, c);
  x = (v ? a : 0.f) / maxv;
  y = (v ? b : 0.f) / maxv;
  z = (v ? c : 0.f) / maxv;
}

__device__ __forceinline__ float get_thresh(int ep) {
  return (float)fmax(0.025 - 0.001 * (double)ep, 0.005);
}

// ================= K1: stats partials; last block reduces, writes scalars, builds planes =================
__global__ __launch_bounds__(256) void k_stats(const float* __restrict__ fake,
                                               const float* __restrict__ real,
                                               float* __restrict__ out,
                                               char* __restrict__ ws) {
  Acc* acc = (Acc*)(ws + kOffAcc);
  unsigned* ctr = (unsigned*)(ws + kOffC1);
  float4* planes = (float4*)(ws + kOffPlanes);
  unsigned long long* sp = (unsigned long long*)(ws + kOffSP);

  const int b = blockIdx.x, t = threadIdx.x;
  const int lane = t & 63, wid = t >> 6;

  __shared__ double sD0[4], sD1[4], sD2[4], sD3[4];
  __shared__ int sI0[4];
  __shared__ float sF0[4];
  __shared__ unsigned sArr;
  __shared__ float sMaxv;

  {
    int i = b * 256 + t;
    int row = i / kW, col = i - row * kW;
    bool vr, vf; float rx, ry, rz, fx, fy, fz;
    pix_coords(real[i], row, col, vr, rx, ry, rz);
    pix_coords(fake[i], row, col, vf, fx, fy, fz);
    double dx2 = 0, dy2 = 0, dz2 = 0, dl2 = 0; int cc = 0;
    if (vr && vf) {
      float ddx = rx - fx, ddy = ry - fy, ddz = rz - fz;
      dx2 = (double)ddx * (double)ddx;
      dy2 = (double)ddy * (double)ddy;
      dz2 = (double)ddz * (double)ddz;
      double dl = log(fabs((double)rz)) - log(fabs((double)fz));
      dl2 = dl * dl;
      cc = 1;
    }
    float mx = vf ? fmaxf(fmaxf(fx, fy), fz) : 0.0f;
    for (int o = 32; o; o >>= 1) {
      dx2 += __shfl_down(dx2, o); dy2 += __shfl_down(dy2, o);
      dz2 += __shfl_down(dz2, o); dl2 += __shfl_down(dl2, o);
      cc += __shfl_down(cc, o);
      mx = fmaxf(mx, __shfl_down(mx, o));
    }
    if (lane == 0) { sD0[wid]=dx2; sD1[wid]=dy2; sD2[wid]=dz2; sD3[wid]=dl2;
                     sI0[wid]=cc; sF0[wid]=mx; }
    __syncthreads();
    if (t == 0) {
      unsigned long long* e = sp + (size_t)b * 6;
      ast64(e + 0, __double_as_longlong(sD0[0]+sD0[1]+sD0[2]+sD0[3]));
      ast64(e + 1, __double_as_longlong(sD1[0]+sD1[1]+sD1[2]+sD1[3]));
      ast64(e + 2, __double_as_longlong(sD2[0]+sD2[1]+sD2[2]+sD2[3]));
      ast64(e + 3, __double_as_longlong(sD3[0]+sD3[1]+sD3[2]+sD3[3]));
      ast64(e + 4, (unsigned long long)(sI0[0]+sI0[1]+sI0[2]+sI0[3]));
      float bm = fmaxf(fmaxf(sF0[0], sF0[1]), fmaxf(sF0[2], sF0[3]));
      ast64(e + 5, (unsigned long long)__float_as_uint(bm));
    }
  }
  __syncthreads();   // drains vmcnt: this block's atomic stores globally performed
  if (t == 0)
    sArr = __hip_atomic_fetch_add(ctr, 1u, __ATOMIC_RELAXED, __HIP_MEMORY_SCOPE_AGENT);
  __syncthreads();
  if (sArr != kPoison + (unsigned)(kB1 - 1)) return;   // only last arrival continues

  // ---- tail: global reduce + scalar losses + plane build ----
  {
    double gx = 0, gy = 0, gz = 0, gl = 0; int gc = 0; float gm = 0.f;
    for (int r = t; r < kB1; r += 256) {
      const unsigned long long* e = sp + (size_t)r * 6;
      gx += __longlong_as_double(ald64(e + 0));
      gy += __longlong_as_double(ald64(e + 1));
      gz += __longlong_as_double(ald64(e + 2));
      gl += __longlong_as_double(ald64(e + 3));
      gc += (int)ald64(e + 4);
      gm = fmaxf(gm, __uint_as_float((unsigned)ald64(e + 5)));
    }
    for (int o = 32; o; o >>= 1) {
      gx += __shfl_down(gx, o); gy += __shfl_down(gy, o);
      gz += __shfl_down(gz, o); gl += __shfl_down(gl, o);
      gc += __shfl_down(gc, o);
      gm = fmaxf(gm, __shfl_down(gm, o));
    }
    if (lane == 0) { sD0[wid]=gx; sD1[wid]=gy; sD2[wid]=gz; sD3[wid]=gl;
                     sI0[wid]=gc; sF0[wid]=gm; }
    __syncthreads();
    if (t == 0) {
      double SX = sD0[0]+sD0[1]+sD0[2]+sD0[3];
      double SY = sD1[0]+sD1[1]+sD1[2]+sD1[3];
      double SZ = sD2[0]+sD2[1]+sD2[2]+sD2[3];
      double SL = sD3[0]+sD3[1]+sD3[2]+sD3[3];
      int CN = sI0[0]+sI0[1]+sI0[2]+sI0[3];
      float MX = fmaxf(fmaxf(sF0[0], sF0[1]), fmaxf(sF0[2], sF0[3]));
      double cntd = (CN > 0) ? (double)CN : 1.0;
      double lossX = sqrt(SX / cntd);
      double lossY = sqrt(SY / cntd);
      double lossZ = sqrt(SZ / cntd);
      double rmse_log = 10000.0 * sqrt(SL / cntd);
      double loss17 = rmse_log * fabs(10.0 * (3.0 - exp(lossX) - exp(lossY) - exp(lossZ)));
      acc->lossX = lossX; acc->lossY = lossY; acc->lossZ = lossZ;
      acc->rmse_log = rmse_log; acc->loss17 = loss17;
      acc->maxv = MX;
      out[0] = (float)rmse_log;
      out[1] = (float)lossX;
      out[2] = (float)lossY;
      out[3] = (float)lossZ;
      out[5] = (float)loss17;
      sMaxv = MX;
    }
    __syncthreads();
  }
  {
    float maxv = sMaxv;
#pragma unroll
    for (int j = 0; j < 4; j++) {
      int pid = t * 4 + j;
      if (pid >= 1000) break;
      float px[3], py[3], pz[3];
#pragma unroll
      for (int v = 0; v < 3; v++) {
        unsigned p = 3u * (unsigned)pid + (unsigned)v;
        unsigned o0, o1;
        threefry(p, p + 3000u, o0, o1);     // JAX randint: multiplier wraps to 0 => o1 % span
        unsigned idx = o1 % kSpan;
        int row = (int)(idx / kW), col = (int)idx - row * kW;
        make_pt(fake[idx], row, col, maxv, px[v], py[v], pz[v]);
      }
      float ax = px[1]-px[0], ay = py[1]-py[0], az = pz[1]-pz[0];
      float bx = px[2]-px[0], by = py[2]-py[0], bz = pz[2]-pz[0];
      float nx = ay*bz - az*by;
      float ny = az*bx - ax*bz;
      float nz = ax*by - ay*bx;
      float nn = sqrtf(nx*nx + ny*ny + nz*nz);
      nx /= nn; ny /= nn; nz /= nn;
      float kk = -(nx*px[1] + ny*py[1] + nz*pz[1]);
      planes[pid] = make_float4(nx, ny, nz, kk);   // plain store: consumed by next kernel
    }
  }
}

// ================= K3: points-in-registers count; last block selects + rotation =================
__global__ __launch_bounds__(256) void k_count(const float* __restrict__ fake,
                                               const int* __restrict__ epoch,
                                               char* __restrict__ ws) {
  Acc* acc = (Acc*)(ws + kOffAcc);
  unsigned* ctr = (unsigned*)(ws + kOffC3);
  const float4* planes = (const float4*)(ws + kOffPlanes);
  unsigned long long* rows = (unsigned long long*)(ws + kOffRows);

  const int b = blockIdx.x, t = threadIdx.x;
  const int lane = t & 63, wid = t >> 6;
  const float th = get_thresh(*epoch);
  const float maxv = acc->maxv;

  __shared__ float4 sPl[1000];
  __shared__ unsigned sCnt[4][512];
  __shared__ unsigned sArr;
  __shared__ unsigned sKey[4];

  // stage all 1000 planes in LDS (read broadcast in the hot loop)
  for (int j = t; j < 1000; j += 256) sPl[j] = planes[j];

  // this thread's 2 points, in registers as packed pairs
  v2f qx, qy, qz;
  {
    int i0 = b * 512 + t, i1 = i0 + 256;
    int r0 = i0 / kW, c0 = i0 - r0 * kW;
    int r1 = i1 / kW, c1 = i1 - r1 * kW;
    float x0, y0, z0, x1, y1, z1;
    make_pt(fake[i0], r0, c0, maxv, x0, y0, z0);
    make_pt(fake[i1], r1, c1, maxv, x1, y1, z1);
    qx = (v2f){x0, x1}; qy = (v2f){y0, y1}; qz = (v2f){z0, z1};
  }
  __syncthreads();

  // 500 plane-pairs; per pair: 2 LDS broadcasts + 6 pk_fma + 4 cmp/ballot
#pragma unroll 4
  for (int jp = 0; jp < 500; ++jp) {
    float4 A = sPl[2 * jp];
    float4 B = sPl[2 * jp + 1];
    v2f dA = __builtin_elementwise_fma(qx, (v2f){A.x, A.x},
             __builtin_elementwise_fma(qy, (v2f){A.y, A.y},
             __builtin_elementwise_fma(qz, (v2f){A.z, A.z}, (v2f){A.w, A.w})));
    v2f dB = __builtin_elementwise_fma(qx, (v2f){B.x, B.x},
             __builtin_elementwise_fma(qy, (v2f){B.y, B.y},
             __builtin_elementwise_fma(qz, (v2f){B.z, B.z}, (v2f){B.w, B.w})));
    unsigned cA = (unsigned)__popcll(__ballot(fabsf(dA.x) <= th)) +
                  (unsigned)__popcll(__ballot(fabsf(dA.y) <= th));
    unsigned cB = (unsigned)__popcll(__ballot(fabsf(dB.x) <= th)) +
                  (unsigned)__popcll(__ballot(fabsf(dB.y) <= th));
    if (lane == 0) sCnt[wid][jp] = cA | (cB << 16);
  }
  __syncthreads();

  // block aggregate: thread t (<250) owns planes 4t..4t+3; packed u16 add is carry-safe (<=512)
  if (t < 250) {
    unsigned p0 = sCnt[0][2*t]   + sCnt[1][2*t]   + sCnt[2][2*t]   + sCnt[3][2*t];
    unsigned p1 = sCnt[0][2*t+1] + sCnt[1][2*t+1] + sCnt[2][2*t+1] + sCnt[3][2*t+1];
    ast64(rows + (size_t)b * 256 + t,
          (unsigned long long)p0 | ((unsigned long long)p1 << 32));
  }
  __syncthreads();   // drains vmcnt
  if (t == 0)
    sArr = __hip_atomic_fetch_add(ctr, 1u, __ATOMIC_RELAXED, __HIP_MEMORY_SCOPE_AGENT);
  __syncthreads();
  if (sArr != kPoison + (unsigned)(kB3 - 1)) return;

  // ---- tail: select best plane (argmax, first index on ties) + rotation ----
  unsigned mykey = 0u;
  if (t < 250) {
    unsigned c0 = 0, c1 = 0, c2 = 0, c3 = 0;
    for (int r = 0; r < kB3; ++r) {
      unsigned long long v = ald64(rows + (size_t)r * 256 + t);
      c0 += (unsigned)(v & 0xFFFFu);
      c1 += (unsigned)((v >> 16) & 0xFFFFu);
      c2 += (unsigned)((v >> 32) & 0xFFFFu);
      c3 += (unsigned)((v >> 48) & 0xFFFFu);
    }
    unsigned tot[4] = {c0, c1, c2, c3};
#pragma unroll
    for (int j = 0; j < 4; ++j) {
      int plane = 4 * t + j;
      int score = ((int)tot[j] > 5000) ? (int)tot[j] : -1;   // MIN_POINTS, strict >
      unsigned key = ((unsigned)(score + 2) << 10) | (unsigned)(1023 - plane);
      mykey = key > mykey ? key : mykey;
    }
  }
  for (int o = 32; o; o >>= 1) {
    unsigned other = __shfl_down(mykey, o);
    mykey = other > mykey ? other : mykey;
  }
  if (lane == 0) sKey[wid] = mykey;
  __syncthreads();
  if (t == 0) {
    unsigned k01 = sKey[0] > sKey[1] ? sKey[0] : sKey[1];
    unsigned k23 = sKey[2] > sKey[3] ? sKey[2] : sKey[3];
    unsigned k = k01 > k23 ? k01 : k23;
    int best = 1023 - (int)(k & 1023u);
    float4 pl = sPl[best];
    float a = pl.x, bb = pl.y, c = pl.z, d = pl.w;
    float n2 = a * a + bb * bb + c * c;
    float cos_t = c / sqrtf(n2);
    float sin_t = sqrtf((a * a + bb * bb) / n2);
    float sab = sqrtf(a * a + bb * bb);
    float u1 = bb / sab, u2 = -a / sab;
    acc->pa = a; acc->pb = bb; acc->pc = c; acc->pd = d;
    acc->r0 = -u2 * sin_t; acc->r1 = u1 * sin_t; acc->r2 = cos_t;
    acc->tz = d / c;                       // plain stores: consumed by next kernel
  }
}

// ================= K5: zc reduction over best plane's inliers; last block finalizes =================
__global__ __launch_bounds__(256) void k_zc(const float* __restrict__ fake,
                                            const int* __restrict__ epoch,
                                            float* __restrict__ out,
                                            char* __restrict__ ws) {
  Acc* acc = (Acc*)(ws + kOffAcc);
  unsigned* ctr = (unsigned*)(ws + kOffC5);
  unsigned long long* zp = (unsigned long long*)(ws + kOffZP);

  const int b = blockIdx.x, t = threadIdx.x;
  const int lane = t & 63, wid = t >> 6;
  const float th = get_thresh(*epoch);
  const float maxv = acc->maxv;
  const float a = acc->pa, bb = acc->pb, c = acc->pc, d = acc->pd;
  const float r0 = acc->r0, r1 = acc->r1, r2 = acc->r2, tz = acc->tz;

  __shared__ double sD0[4];
  __shared__ int sI0[4];
  __shared__ float sF0[4], sF1[4];
  __shared__ unsigned sArr;

  double sz = 0.0; int ic = 0; float zmx = -INFINITY, zmn = -INFINITY;  // zmn = max(-zc)
  {
    int i = b * 256 + t;
    int row = i / kW, col = i - row * kW;
    float qx, qy, qz;
    make_pt(fake[i], row, col, maxv, qx, qy, qz);
    // identical per-lane fma chain to k_count (v_pk_fma_f32 == fmaf per lane)
    float dist = fmaf(qx, a, fmaf(qy, bb, fmaf(qz, c, d)));
    if (fabsf(dist) <= th) {
      float zc = fmaf(qx, r0, fmaf(qy, r1, (qz + tz) * r2));
      sz = (double)zc; ic = 1; zmx = zc; zmn = -zc;
    }
  }
  for (int o = 32; o; o >>= 1) {
    sz += __shfl_down(sz, o); ic += __shfl_down(ic, o);
    zmx = fmaxf(zmx, __shfl_down(zmx, o));
    zmn = fmaxf(zmn, __shfl_down(zmn, o));
  }
  if (lane == 0) { sD0[wid] = sz; sI0[wid] = ic; sF0[wid] = zmx; sF1[wid] = zmn; }
  __syncthreads();
  if (t == 0) {
    unsigned long long* e = zp + (size_t)b * 4;
    ast64(e + 0, __double_as_longlong(sD0[0]+sD0[1]+sD0[2]+sD0[3]));
    ast64(e + 1, (unsigned long long)(sI0[0]+sI0[1]+sI0[2]+sI0[3]));
    float bmx = fmaxf(fmaxf(sF0[0], sF0[1]), fmaxf(sF0[2], sF0[3]));
    float bmn = fmaxf(fmaxf(sF1[0], sF1[1]), fmaxf(sF1[2], sF1[3]));
    ast64(e + 2, (unsigned long long)__float_as_uint(bmx) |
                 ((unsigned long long)__float_as_uint(bmn) << 32));
  }
  __syncthreads();   // drains vmcnt
  if (t == 0)
    sArr = __hip_atomic_fetch_add(ctr, 1u, __ATOMIC_RELAXED, __HIP_MEMORY_SCOPE_AGENT);
  __syncthreads();
  if (sArr != kPoison + (unsigned)(kB5 - 1)) return;

  // ---- tail: final pmdg ----
  {
    double gs = 0.0; int gi = 0; float gmx = -INFINITY, gmn = -INFINITY;
    for (int r = t; r < kB5; r += 256) {
      const unsigned long long* e = zp + (size_t)r * 4;
      gs += __longlong_as_double(ald64(e + 0));
      gi += (int)ald64(e + 1);
      unsigned long long mm = ald64(e + 2);
      gmx = fmaxf(gmx, __uint_as_float((unsigned)(mm & 0xFFFFFFFFu)));
      gmn = fmaxf(gmn, __uint_as_float((unsigned)(mm >> 32)));
    }
    for (int o = 32; o; o >>= 1) {
      gs += __shfl_down(gs, o); gi += __shfl_down(gi, o);
      gmx = fmaxf(gmx, __shfl_down(gmx, o));
      gmn = fmaxf(gmn, __shfl_down(gmn, o));
    }
    if (lane == 0) { sD0[wid] = gs; sI0[wid] = gi; sF0[wid] = gmx; sF1[wid] = gmn; }
    __syncthreads();
    if (t == 0) {
      double S = sD0[0]+sD0[1]+sD0[2]+sD0[3];
      int IC = sI0[0]+sI0[1]+sI0[2]+sI0[3];
      float MX = fmaxf(fmaxf(sF0[0], sF0[1]), fmaxf(sF0[2], sF0[3]));
      float MN = fmaxf(fmaxf(sF1[0], sF1[1]), fmaxf(sF1[2], sF1[3]));
      double below = 0.0, above = 0.0;
      if (IC > 0) {
        double icd = (double)IC;
        double mean = S / icd;
        below = (double)MX - mean;    // sum(|zc - zmax|)/icnt  (all zc <= zmax)
        above = mean - (double)(-MN); // sum(|zc - zmin|)/icnt
      }
      if (above == 0.0) above = 1e-7;
      double pmdg = 1000.0 * (above + below);
      out[4] = (float)pmdg;
      out[6] = (float)(acc->loss17 + pmdg);
    }
  }
}

}  // namespace

extern "C" void kernel_launch(void* const* d_in, const int* in_sizes, int n_in,
                              void* d_out, int out_size, void* d_ws, size_t ws_size,
                              hipStream_t stream) {
  (void)in_sizes; (void)n_in; (void)out_size; (void)ws_size;
  const float* fake = (const float*)d_in[0];
  const float* real = (const float*)d_in[1];
  const int* epoch = (const int*)d_in[2];
  float* out = (float*)d_out;
  char* ws = (char*)d_ws;

  k_stats<<<kB1, 256, 0, stream>>>(fake, real, out, ws);
  k_count<<<kB3, 256, 0, stream>>>(fake, epoch, ws);
  k_zc<<<kB5, 256, 0, stream>>>(fake, epoch, out, ws);
}

// Round 5
// 136.867 us; speedup vs baseline: 2.6328x; 1.3156x over previous
//
#include <hip/hip_runtime.h>

namespace {

typedef float v2f __attribute__((ext_vector_type(2)));

constexpr int kW = 640;
constexpr int kN = 230400;            // 360*640
constexpr unsigned kSpan = 230400u;
constexpr int kB1 = 900;              // stats blocks (256 pts each)
constexpr int kB3 = 1024;             // count blocks (225 pts each)
constexpr int kPPB3 = 225;            // points per count block
constexpr int kB5 = 900;              // zc blocks (256 pts each)
constexpr unsigned kPoison = 0xAAAAAAAAu;

struct __align__(16) Acc {            // handed across kernels via stream order
  double lossX, lossY, lossZ, rmse_log, loss17;
  float maxv;
  unsigned selkey;                    // ((score+2)<<10) | (1023-plane), atomicMax target
};

// ws layout (bytes)
constexpr size_t kOffAcc     = 0;
constexpr size_t kOffC1      = 256;    // k_stats arrival counter (poison-based)
constexpr size_t kOffC3      = 320;    // k_count arrival counter
constexpr size_t kOffC5      = 384;    // k_zc arrival counter
constexpr size_t kOffPlanes  = 512;                      // 1024 * 16 = 16384
constexpr size_t kOffSP      = 512 + 16384;              // 900 * 48 = 43200
constexpr size_t kOffZP      = kOffSP + 43200;           // 900 * 32 = 28800
constexpr size_t kOffPartial = kOffZP + 28800;           // 1024 * 256 * 4 = 1 MB
constexpr size_t kOffPts     = kOffPartial + (size_t)kB3 * 256 * 4;  // 230400*16 = 3.69 MB
// total ~4.8 MB

__device__ __forceinline__ void ast64(unsigned long long* p, unsigned long long v) {
  __hip_atomic_store(p, v, __ATOMIC_RELAXED, __HIP_MEMORY_SCOPE_AGENT);
}
__device__ __forceinline__ unsigned long long ald64(const unsigned long long* p) {
  return __hip_atomic_load(p, __ATOMIC_RELAXED, __HIP_MEMORY_SCOPE_AGENT);
}
__device__ __forceinline__ void ast32(unsigned* p, unsigned v) {
  __hip_atomic_store(p, v, __ATOMIC_RELAXED, __HIP_MEMORY_SCOPE_AGENT);
}
__device__ __forceinline__ unsigned ald32(const unsigned* p) {
  return __hip_atomic_load(p, __ATOMIC_RELAXED, __HIP_MEMORY_SCOPE_AGENT);
}

__device__ __forceinline__ unsigned rotl32(unsigned v, int r) {
  return (v << r) | (v >> (32 - r));
}

// Threefry-2x32, 20 rounds, key = (0, 42)  [jax.random.key(42)]
__device__ __forceinline__ void threefry(unsigned c0, unsigned c1,
                                         unsigned& o0, unsigned& o1) {
  const unsigned ks0 = 0u, ks1 = 42u, ks2 = 0x1BD11BDAu ^ 0u ^ 42u;
  unsigned x0 = c0 + ks0, x1 = c1 + ks1;
#define TFR(r) { x0 += x1; x1 = rotl32(x1, (r)); x1 ^= x0; }
  TFR(13) TFR(15) TFR(26) TFR(6)
  x0 += ks1; x1 += ks2 + 1u;
  TFR(17) TFR(29) TFR(16) TFR(24)
  x0 += ks2; x1 += ks0 + 2u;
  TFR(13) TFR(15) TFR(26) TFR(6)
  x0 += ks0; x1 += ks1 + 3u;
  TFR(17) TFR(29) TFR(16) TFR(24)
  x0 += ks1; x1 += ks2 + 4u;
  TFR(13) TFR(15) TFR(26) TFR(6)
  x0 += ks2; x1 += ks0 + 5u;
#undef TFR
  o0 = x0; o1 = x1;
}

__device__ __forceinline__ void pix_coords(float d, int row, int col, bool& valid,
                                           float& x, float& y, float& z) {
  valid = (d > 0.0f) && (d < 65535.0f);
  float z0 = d / 1000.0f;
  float x0 = z0 * ((float)col - 334.081f) / 460.585f;
  float y0 = z0 * ((float)row - 169.808f) / 460.268f;
  x = x0 * 1000.0f;
  y = y0 * 1000.0f;
  z = z0 * 1000.0f;
  if (x == 0.0f) x = 1e-7f;
  if (y == 0.0f) y = 1e-7f;
  if (z == 0.0f) z = 1e-7f;
}

// normalized point — identical expression wherever used (bitwise mask consistency)
__device__ __forceinline__ void make_pt(float d, int row, int col, float maxv,
                                        float& x, float& y, float& z) {
  bool v; float a, b, c;
  pix_coords(d, row, col, v, a, b, c);
  x = (v ? a : 0.f) / maxv;
  y = (v ? b : 0.f) / maxv;
  z = (v ? c : 0.f) / maxv;
}

__device__ __forceinline__ float get_thresh(int ep) {
  return (float)fmax(0.025 - 0.001 * (double)ep, 0.005);
}

// ================= K1: stats partials + raw pts; last block reduces, scalars, planes =================
__global__ __launch_bounds__(256) void k_stats(const float* __restrict__ fake,
                                               const float* __restrict__ real,
                                               float* __restrict__ out,
                                               char* __restrict__ ws) {
  Acc* acc = (Acc*)(ws + kOffAcc);
  unsigned* ctr = (unsigned*)(ws + kOffC1);
  float4* planes = (float4*)(ws + kOffPlanes);
  unsigned long long* sp = (unsigned long long*)(ws + kOffSP);
  float4* ptsraw = (float4*)(ws + kOffPts);

  const int b = blockIdx.x, t = threadIdx.x;
  const int lane = t & 63, wid = t >> 6;

  __shared__ double sD0[4], sD1[4], sD2[4], sD3[4];
  __shared__ int sI0[4];
  __shared__ float sF0[4];
  __shared__ unsigned sArr;
  __shared__ float sMaxv;

  {
    int i = b * 256 + t;
    int row = i / kW, col = i - row * kW;
    bool vr, vf; float rx, ry, rz, fx, fy, fz;
    pix_coords(real[i], row, col, vr, rx, ry, rz);
    pix_coords(fake[i], row, col, vf, fx, fy, fz);
    // raw (unnormalized, mask-applied) point for later kernels — plain store,
    // consumed only by later kernels in the same stream (visibility guaranteed)
    ptsraw[i] = make_float4(vf ? fx : 0.f, vf ? fy : 0.f, vf ? fz : 0.f, 0.f);
    double dx2 = 0, dy2 = 0, dz2 = 0, dl2 = 0; int cc = 0;
    if (vr && vf) {
      float ddx = rx - fx, ddy = ry - fy, ddz = rz - fz;
      dx2 = (double)ddx * (double)ddx;
      dy2 = (double)ddy * (double)ddy;
      dz2 = (double)ddz * (double)ddz;
      double dl = log(fabs((double)rz)) - log(fabs((double)fz));
      dl2 = dl * dl;
      cc = 1;
    }
    float mx = vf ? fmaxf(fmaxf(fx, fy), fz) : 0.0f;
    for (int o = 32; o; o >>= 1) {
      dx2 += __shfl_down(dx2, o); dy2 += __shfl_down(dy2, o);
      dz2 += __shfl_down(dz2, o); dl2 += __shfl_down(dl2, o);
      cc += __shfl_down(cc, o);
      mx = fmaxf(mx, __shfl_down(mx, o));
    }
    if (lane == 0) { sD0[wid]=dx2; sD1[wid]=dy2; sD2[wid]=dz2; sD3[wid]=dl2;
                     sI0[wid]=cc; sF0[wid]=mx; }
    __syncthreads();
    if (t == 0) {
      unsigned long long* e = sp + (size_t)b * 6;
      ast64(e + 0, __double_as_longlong(sD0[0]+sD0[1]+sD0[2]+sD0[3]));
      ast64(e + 1, __double_as_longlong(sD1[0]+sD1[1]+sD1[2]+sD1[3]));
      ast64(e + 2, __double_as_longlong(sD2[0]+sD2[1]+sD2[2]+sD2[3]));
      ast64(e + 3, __double_as_longlong(sD3[0]+sD3[1]+sD3[2]+sD3[3]));
      ast64(e + 4, (unsigned long long)(sI0[0]+sI0[1]+sI0[2]+sI0[3]));
      float bm = fmaxf(fmaxf(sF0[0], sF0[1]), fmaxf(sF0[2], sF0[3]));
      ast64(e + 5, (unsigned long long)__float_as_uint(bm));
    }
  }
  __syncthreads();   // drains vmcnt: this block's atomic stores globally performed
  if (t == 0)
    sArr = __hip_atomic_fetch_add(ctr, 1u, __ATOMIC_RELAXED, __HIP_MEMORY_SCOPE_AGENT);
  __syncthreads();
  if (sArr != kPoison + (unsigned)(kB1 - 1)) return;   // only last arrival continues

  // ---- tail: global reduce + scalar losses + plane build ----
  {
    double gx = 0, gy = 0, gz = 0, gl = 0; int gc = 0; float gm = 0.f;
    for (int r = t; r < kB1; r += 256) {
      const unsigned long long* e = sp + (size_t)r * 6;
      gx += __longlong_as_double(ald64(e + 0));
      gy += __longlong_as_double(ald64(e + 1));
      gz += __longlong_as_double(ald64(e + 2));
      gl += __longlong_as_double(ald64(e + 3));
      gc += (int)ald64(e + 4);
      gm = fmaxf(gm, __uint_as_float((unsigned)ald64(e + 5)));
    }
    for (int o = 32; o; o >>= 1) {
      gx += __shfl_down(gx, o); gy += __shfl_down(gy, o);
      gz += __shfl_down(gz, o); gl += __shfl_down(gl, o);
      gc += __shfl_down(gc, o);
      gm = fmaxf(gm, __shfl_down(gm, o));
    }
    if (lane == 0) { sD0[wid]=gx; sD1[wid]=gy; sD2[wid]=gz; sD3[wid]=gl;
                     sI0[wid]=gc; sF0[wid]=gm; }
    __syncthreads();
    if (t == 0) {
      double SX = sD0[0]+sD0[1]+sD0[2]+sD0[3];
      double SY = sD1[0]+sD1[1]+sD1[2]+sD1[3];
      double SZ = sD2[0]+sD2[1]+sD2[2]+sD2[3];
      double SL = sD3[0]+sD3[1]+sD3[2]+sD3[3];
      int CN = sI0[0]+sI0[1]+sI0[2]+sI0[3];
      float MX = fmaxf(fmaxf(sF0[0], sF0[1]), fmaxf(sF0[2], sF0[3]));
      double cntd = (CN > 0) ? (double)CN : 1.0;
      double lossX = sqrt(SX / cntd);
      double lossY = sqrt(SY / cntd);
      double lossZ = sqrt(SZ / cntd);
      double rmse_log = 10000.0 * sqrt(SL / cntd);
      double loss17 = rmse_log * fabs(10.0 * (3.0 - exp(lossX) - exp(lossY) - exp(lossZ)));
      acc->lossX = lossX; acc->lossY = lossY; acc->lossZ = lossZ;
      acc->rmse_log = rmse_log; acc->loss17 = loss17;
      acc->maxv = MX;
      acc->selkey = 0u;                 // atomicMax target for k_count's select
      out[0] = (float)rmse_log;
      out[1] = (float)lossX;
      out[2] = (float)lossY;
      out[3] = (float)lossZ;
      out[5] = (float)loss17;
      sMaxv = MX;
    }
    __syncthreads();
  }
  {
    float maxv = sMaxv;
#pragma unroll
    for (int j = 0; j < 4; j++) {
      int pid = t * 4 + j;                 // covers 0..1023
      if (pid < 1000) {
        float px[3], py[3], pz[3];
#pragma unroll
        for (int v = 0; v < 3; v++) {
          unsigned p = 3u * (unsigned)pid + (unsigned)v;
          unsigned o0, o1;
          threefry(p, p + 3000u, o0, o1);  // JAX randint: multiplier wraps to 0 => o1 % span
          unsigned idx = o1 % kSpan;
          int row = (int)(idx / kW), col = (int)idx - row * kW;
          make_pt(fake[idx], row, col, maxv, px[v], py[v], pz[v]);
        }
        float ax = px[1]-px[0], ay = py[1]-py[0], az = pz[1]-pz[0];
        float bx = px[2]-px[0], by = py[2]-py[0], bz = pz[2]-pz[0];
        float nx = ay*bz - az*by;
        float ny = az*bx - ax*bz;
        float nz = ax*by - ay*bx;
        float nn = sqrtf(nx*nx + ny*ny + nz*nz);
        nx /= nn; ny /= nn; nz /= nn;
        float kk = -(nx*px[1] + ny*py[1] + nz*pz[1]);
        planes[pid] = make_float4(nx, ny, nz, kk);
      } else {
        planes[pid] = make_float4(0.f, 0.f, 0.f, 3e38f);  // dummy: never an inlier
      }
    }
  }
}

// ================= K3: planes-in-VGPR count; counts never leave registers =================
__global__ __launch_bounds__(256) void k_count(const int* __restrict__ epoch,
                                               char* __restrict__ ws) {
  Acc* acc = (Acc*)(ws + kOffAcc);
  unsigned* ctr = (unsigned*)(ws + kOffC3);
  const float4* planes = (const float4*)(ws + kOffPlanes);
  unsigned* partial = (unsigned*)(ws + kOffPartial);
  const float4* ptsraw = (const float4*)(ws + kOffPts);

  const int b = blockIdx.x, t = threadIdx.x;
  const float th = get_thresh(*epoch);
  const float maxv = acc->maxv;

  __shared__ float4 sPts[kPPB3];
  __shared__ uint4 sAcc[16][16];
  __shared__ unsigned sArr;

  // stage this block's 225 points, normalized (identical expression to k_zc)
  if (t < kPPB3) {
    float4 r = ptsraw[b * kPPB3 + t];
    sPts[t] = make_float4(r.x / maxv, r.y / maxv, r.z / maxv, 0.f);
  }
  // each lane owns 4 planes in registers (pairs for pk_fma)
  float4 p0 = planes[t * 4 + 0], p1 = planes[t * 4 + 1];
  float4 p2 = planes[t * 4 + 2], p3 = planes[t * 4 + 3];
  v2f Ax = {p0.x, p1.x}, Ay = {p0.y, p1.y}, Az = {p0.z, p1.z}, Aw = {p0.w, p1.w};
  v2f Bx = {p2.x, p3.x}, By = {p2.y, p3.y}, Bz = {p2.z, p3.z}, Bw = {p2.w, p3.w};
  __syncthreads();

  int c0 = 0, c1 = 0, c2 = 0, c3 = 0;
#pragma unroll 5
  for (int s = 0; s < kPPB3; ++s) {
    float4 q = sPts[s];                    // broadcast ds_read_b128
    v2f qx = {q.x, q.x}, qy = {q.y, q.y}, qz = {q.z, q.z};
    // per-half chain == fmaf(qx, a, fmaf(qy, b, fmaf(qz, c, d))) — matches k_zc
    v2f dA = __builtin_elementwise_fma(qx, Ax,
             __builtin_elementwise_fma(qy, Ay,
             __builtin_elementwise_fma(qz, Az, Aw)));
    v2f dB = __builtin_elementwise_fma(qx, Bx,
             __builtin_elementwise_fma(qy, By,
             __builtin_elementwise_fma(qz, Bz, Bw)));
    c0 += (fabsf(dA.x) <= th) ? 1 : 0;
    c1 += (fabsf(dA.y) <= th) ? 1 : 0;
    c2 += (fabsf(dB.x) <= th) ? 1 : 0;
    c3 += (fabsf(dB.y) <= th) ? 1 : 0;
  }
  // counts <= 225 fit u8; one packed store per thread for the whole kernel
  ast32(&partial[b * 256 + t],
        (unsigned)c0 | ((unsigned)c1 << 8) | ((unsigned)c2 << 16) | ((unsigned)c3 << 24));

  __syncthreads();   // drains vmcnt
  if (t == 0)
    sArr = __hip_atomic_fetch_add(ctr, 1u, __ATOMIC_RELAXED, __HIP_MEMORY_SCOPE_AGENT);
  __syncthreads();
  unsigned ret = sArr;
  if (ret < kPoison + (unsigned)(kB3 - 16)) return;

  // ---- stage 1+2 select: last 16 arrivals each own 16 owner-threads (64 planes) ----
  int r = (int)(ret - (kPoison + (unsigned)(kB3 - 16)));   // 0..15
  if (t == 0) {
    while (ald32(ctr) != kPoison + (unsigned)kB3) __builtin_amdgcn_s_sleep(2);
  }
  __syncthreads();

  int owner = r * 16 + (t & 15);        // global owner-thread index 0..255
  int chunk = t >> 4;                   // 16 row-chunks of 64 rows
  unsigned s0 = 0, s1 = 0, s2 = 0, s3 = 0;
  for (int row = chunk * 64; row < chunk * 64 + 64; ++row) {
    unsigned v = ald32(&partial[row * 256 + owner]);
    s0 += v & 0xFFu; s1 += (v >> 8) & 0xFFu;
    s2 += (v >> 16) & 0xFFu; s3 += (v >> 24) & 0xFFu;
  }
  sAcc[t & 15][chunk] = make_uint4(s0, s1, s2, s3);
  __syncthreads();

  unsigned mykey = 0u;
  if (t < 16) {
    unsigned t0 = 0, t1 = 0, t2 = 0, t3 = 0;
    for (int j = 0; j < 16; ++j) {
      uint4 v = sAcc[t][j];
      t0 += v.x; t1 += v.y; t2 += v.z; t3 += v.w;
    }
    unsigned tot[4] = {t0, t1, t2, t3};
    int pbase = (r * 16 + t) * 4;
#pragma unroll
    for (int k = 0; k < 4; ++k) {
      int p = pbase + k;
      if (p < 1000) {
        int score = ((int)tot[k] > 5000) ? (int)tot[k] : -1;   // MIN_POINTS, strict >
        unsigned key = ((unsigned)(score + 2) << 10) | (unsigned)(1023 - p);
        mykey = key > mykey ? key : mykey;
      }
    }
  }
  for (int o = 32; o; o >>= 1) {
    unsigned other = __shfl_down(mykey, o);
    mykey = other > mykey ? other : mykey;
  }
  if (t == 0) atomicMax(&acc->selkey, mykey);
}

// ================= K5: zc reduction over best plane's inliers; last block finalizes =================
__global__ __launch_bounds__(256) void k_zc(const int* __restrict__ epoch,
                                            float* __restrict__ out,
                                            char* __restrict__ ws) {
  Acc* acc = (Acc*)(ws + kOffAcc);
  unsigned* ctr = (unsigned*)(ws + kOffC5);
  const float4* planes = (const float4*)(ws + kOffPlanes);
  unsigned long long* zp = (unsigned long long*)(ws + kOffZP);
  const float4* ptsraw = (const float4*)(ws + kOffPts);

  const int b = blockIdx.x, t = threadIdx.x;
  const int lane = t & 63, wid = t >> 6;
  const float th = get_thresh(*epoch);
  const float maxv = acc->maxv;

  // best plane + rotation derived per block (cheap, uniform)
  int best = 1023 - (int)(acc->selkey & 1023u);
  float4 pl = planes[best];
  const float a = pl.x, bb = pl.y, c = pl.z, d = pl.w;
  float n2 = a * a + bb * bb + c * c;
  float cos_t = c / sqrtf(n2);
  float sin_t = sqrtf((a * a + bb * bb) / n2);
  float sab = sqrtf(a * a + bb * bb);
  float u1 = bb / sab, u2 = -a / sab;
  const float r0 = -u2 * sin_t, r1 = u1 * sin_t, r2 = cos_t, tz = d / c;

  __shared__ double sD0[4];
  __shared__ int sI0[4];
  __shared__ float sF0[4], sF1[4];
  __shared__ unsigned sArr;

  double sz = 0.0; int ic = 0; float zmx = -INFINITY, zmn = -INFINITY;  // zmn = max(-zc)
  {
    float4 rw = ptsraw[b * 256 + t];
    float qx = rw.x / maxv, qy = rw.y / maxv, qz = rw.z / maxv;
    // identical per-lane chain to k_count's pk_fma halves
    float dist = fmaf(qx, a, fmaf(qy, bb, fmaf(qz, c, d)));
    if (fabsf(dist) <= th) {
      float zc = fmaf(qx, r0, fmaf(qy, r1, (qz + tz) * r2));
      sz = (double)zc; ic = 1; zmx = zc; zmn = -zc;
    }
  }
  for (int o = 32; o; o >>= 1) {
    sz += __shfl_down(sz, o); ic += __shfl_down(ic, o);
    zmx = fmaxf(zmx, __shfl_down(zmx, o));
    zmn = fmaxf(zmn, __shfl_down(zmn, o));
  }
  if (lane == 0) { sD0[wid] = sz; sI0[wid] = ic; sF0[wid] = zmx; sF1[wid] = zmn; }
  __syncthreads();
  if (t == 0) {
    unsigned long long* e = zp + (size_t)b * 4;
    ast64(e + 0, __double_as_longlong(sD0[0]+sD0[1]+sD0[2]+sD0[3]));
    ast64(e + 1, (unsigned long long)(sI0[0]+sI0[1]+sI0[2]+sI0[3]));
    float bmx = fmaxf(fmaxf(sF0[0], sF0[1]), fmaxf(sF0[2], sF0[3]));
    float bmn = fmaxf(fmaxf(sF1[0], sF1[1]), fmaxf(sF1[2], sF1[3]));
    ast64(e + 2, (unsigned long long)__float_as_uint(bmx) |
                 ((unsigned long long)__float_as_uint(bmn) << 32));
  }
  __syncthreads();   // drains vmcnt
  if (t == 0)
    sArr = __hip_atomic_fetch_add(ctr, 1u, __ATOMIC_RELAXED, __HIP_MEMORY_SCOPE_AGENT);
  __syncthreads();
  if (sArr != kPoison + (unsigned)(kB5 - 1)) return;

  // ---- tail: final pmdg ----
  {
    double gs = 0.0; int gi = 0; float gmx = -INFINITY, gmn = -INFINITY;
    for (int r = t; r < kB5; r += 256) {
      const unsigned long long* e = zp + (size_t)r * 4;
      gs += __longlong_as_double(ald64(e + 0));
      gi += (int)ald64(e + 1);
      unsigned long long mm = ald64(e + 2);
      gmx = fmaxf(gmx, __uint_as_float((unsigned)(mm & 0xFFFFFFFFu)));
      gmn = fmaxf(gmn, __uint_as_float((unsigned)(mm >> 32)));
    }
    for (int o = 32; o; o >>= 1) {
      gs += __shfl_down(gs, o); gi += __shfl_down(gi, o);
      gmx = fmaxf(gmx, __shfl_down(gmx, o));
      gmn = fmaxf(gmn, __shfl_down(gmn, o));
    }
    if (lane == 0) { sD0[wid] = gs; sI0[wid] = gi; sF0[wid] = gmx; sF1[wid] = gmn; }
    __syncthreads();
    if (t == 0) {
      double S = sD0[0]+sD0[1]+sD0[2]+sD0[3];
      int IC = sI0[0]+sI0[1]+sI0[2]+sI0[3];
      float MX = fmaxf(fmaxf(sF0[0], sF0[1]), fmaxf(sF0[2], sF0[3]));
      float MN = fmaxf(fmaxf(sF1[0], sF1[1]), fmaxf(sF1[2], sF1[3]));
      double below = 0.0, above = 0.0;
      if (IC > 0) {
        double icd = (double)IC;
        double mean = S / icd;
        below = (double)MX - mean;    // sum(|zc - zmax|)/icnt  (all zc <= zmax)
        above = mean - (double)(-MN); // sum(|zc - zmin|)/icnt
      }
      if (above == 0.0) above = 1e-7;
      double pmdg = 1000.0 * (above + below);
      out[4] = (float)pmdg;
      out[6] = (float)(acc->loss17 + pmdg);
    }
  }
}

}  // namespace

extern "C" void kernel_launch(void* const* d_in, const int* in_sizes, int n_in,
                              void* d_out, int out_size, void* d_ws, size_t ws_size,
                              hipStream_t stream) {
  (void)in_sizes; (void)n_in; (void)out_size; (void)ws_size;
  const float* fake = (const float*)d_in[0];
  const float* real = (const float*)d_in[1];
  const int* epoch = (const int*)d_in[2];
  float* out = (float*)d_out;
  char* ws = (char*)d_ws;

  k_stats<<<kB1, 256, 0, stream>>>(fake, real, out, ws);
  k_count<<<kB3, 256, 0, stream>>>(epoch, ws);
  k_zc<<<kB5, 256, 0, stream>>>(epoch, out, ws);
}